// Round 1
// baseline (378.333 us; speedup 1.0000x reference)
//
#include <hip/hip_runtime.h>

// WaveletPatcher: 3-level a-trous db4 SWT (periodic) + overlapping patch extract.
// x: (64, 4096, 32) f32  ->  out: (64*511, 32*4, 16) f32
//
// Derivation of the conv (XLA conv = cross-correlation, filters pre-reversed,
// pad = [3d left, 4d right] periodic):
//   A_{l+1}[t] = sum_j LO[j] * A_l[(t + (4-j)*d) & 4095],  d = 2^l
// Coefficient channel order in output: c=0:A3, c=1:D3, c=2:D2, c=3:D1.
// out flat index: (b*511 + p)*2048 + n*64 + c*16 + j,  t = 8p + j.

#define T_LEN    4096
#define T_MASK   4095
#define NPATCH   511
#define NCHAN    32
#define NTHREADS 256
#define TPT      (T_LEN / NTHREADS)  // 16 time points per thread

__device__ __constant__ float c_lo[8] = {
    -0.010597401784997278f, 0.032883011666982945f, 0.030841381835986965f,
    -0.18703481171888114f, -0.02798376941698385f, 0.6308807679295904f,
    0.7148465705525415f,   0.23037781330885523f};
__device__ __constant__ float c_hi[8] = {
    -0.23037781330885523f, 0.7148465705525415f, -0.6308807679295904f,
    -0.02798376941698385f, 0.18703481171888114f, 0.030841381835986965f,
    -0.032883011666982945f, -0.010597401784997278f};

// write coefficient value for time t into the (up to 2) patches containing t.
// Each (p,j) cell is written exactly once across t: j<8 from p=t>>3, j>=8 from p=(t>>3)-1.
__device__ __forceinline__ void write_coef(float* __restrict__ out_bn, int c, int t, float v) {
    const int p1 = t >> 3;
    const int j  = t & 7;
    if (p1 <= NPATCH - 1) out_bn[(size_t)p1 * 2048 + c * 16 + j] = v;
    if (p1 >= 1)          out_bn[(size_t)(p1 - 1) * 2048 + c * 16 + j + 8] = v;
}

__global__ __launch_bounds__(NTHREADS) void swt_patch(const float* __restrict__ x,
                                                      float* __restrict__ out) {
    __shared__ float bufA[T_LEN];  // 16 KB
    __shared__ float bufB[T_LEN];  // 16 KB

    // XCD swizzle: blocks are dispatched round-robin over 8 XCDs (i%8).
    // Map so all 32 n-blocks of one b share i%8 -> same XCD -> L2 absorbs
    // the 16x reuse of each 64B input line across n-blocks.
    const int i = blockIdx.x;       // 0..2047
    const int r = i & 7;
    const int q = i >> 3;           // 0..255
    const int b = r + 8 * (q >> 5); // 0..63
    const int n = q & 31;
    const int tid = threadIdx.x;

    // Load series x[b, :, n] (stride 32 floats) into LDS.
    const float* xp = x + (size_t)b * T_LEN * NCHAN + n;
#pragma unroll
    for (int k = 0; k < TPT; ++k) {
        const int t = tid + k * NTHREADS;
        bufA[t] = xp[(size_t)t * NCHAN];
    }
    __syncthreads();

    float* out_bn = out + (size_t)b * NPATCH * 2048 + (size_t)n * 64;

    // ---- level 1: src=bufA(x), A1->bufB, D1->c=3 ----
#pragma unroll
    for (int k = 0; k < TPT; ++k) {
        const int t = tid + k * NTHREADS;
        float a = 0.f, dd = 0.f;
#pragma unroll
        for (int j = 0; j < 8; ++j) {
            const float s = bufA[(t + (4 - j)) & T_MASK];
            a  = fmaf(c_lo[j], s, a);
            dd = fmaf(c_hi[j], s, dd);
        }
        bufB[t] = a;
        write_coef(out_bn, 3, t, dd);
    }
    __syncthreads();

    // ---- level 2: src=bufB(A1), A2->bufA, D2->c=2 ----
#pragma unroll
    for (int k = 0; k < TPT; ++k) {
        const int t = tid + k * NTHREADS;
        float a = 0.f, dd = 0.f;
#pragma unroll
        for (int j = 0; j < 8; ++j) {
            const float s = bufB[(t + 2 * (4 - j)) & T_MASK];
            a  = fmaf(c_lo[j], s, a);
            dd = fmaf(c_hi[j], s, dd);
        }
        bufA[t] = a;
        write_coef(out_bn, 2, t, dd);
    }
    __syncthreads();

    // ---- level 3: src=bufA(A2), A3->c=0, D3->c=1 ----
#pragma unroll
    for (int k = 0; k < TPT; ++k) {
        const int t = tid + k * NTHREADS;
        float a = 0.f, dd = 0.f;
#pragma unroll
        for (int j = 0; j < 8; ++j) {
            const float s = bufA[(t + 4 * (4 - j)) & T_MASK];
            a  = fmaf(c_lo[j], s, a);
            dd = fmaf(c_hi[j], s, dd);
        }
        write_coef(out_bn, 0, t, a);
        write_coef(out_bn, 1, t, dd);
    }
}

extern "C" void kernel_launch(void* const* d_in, const int* in_sizes, int n_in,
                              void* d_out, int out_size, void* d_ws, size_t ws_size,
                              hipStream_t stream) {
    const float* x = (const float*)d_in[0];
    float* out = (float*)d_out;
    hipLaunchKernelGGL(swt_patch, dim3(64 * 32), dim3(NTHREADS), 0, stream, x, out);
}

// Round 2
// 318.289 us; speedup vs baseline: 1.1886x; 1.1886x over previous
//
#include <hip/hip_runtime.h>

// WaveletPatcher: 3-level a-trous db4 SWT (periodic) + overlapping patch extract.
// x: (64, 4096, 32) f32  ->  out: (64*511, 32*4, 16) f32
//
//   A_{l+1}[t] = sum_j LO[j] * A_l[(t + (4-j)*d) & 4095],  d = 2^l   (XLA conv derivation)
// Channel order c=0:A3, 1:D3, 2:D2, 3:D1.  out[(b*511+p)*2048 + n*64 + c*16 + j], t = 8p+j.
//
// R1 lesson: scalar scattered stores assembling 128B lines across phases -> L2 RMW
// amplification. R2: stage coeffs in LDS, write c-pairs (full 128B lines) with float4;
// vectorize conv LDS reads via ds_read_b128 windows (thread computes 4 consecutive t).

#define T_LEN    4096
#define T_MASK   4095
#define NPATCH   511
#define NCHAN    32
#define NTHREADS 256

__device__ __constant__ float c_lo[8] = {
    -0.010597401784997278f, 0.032883011666982945f, 0.030841381835986965f,
    -0.18703481171888114f, -0.02798376941698385f, 0.6308807679295904f,
    0.7148465705525415f,   0.23037781330885523f};
__device__ __constant__ float c_hi[8] = {
    -0.23037781330885523f, 0.7148465705525415f, -0.6308807679295904f,
    -0.02798376941698385f, 0.18703481171888114f, 0.030841381835986965f,
    -0.032883011666982945f, -0.010597401784997278f};

// Store one c-pair (cbase, cbase+1) for all 511 patches: every 128B output line
// (32 floats = two channels' 16 j) is written whole by consecutive float4 stores.
__device__ __forceinline__ void store_pair(float* __restrict__ out_bn, int cbase,
                                           const float* __restrict__ bufLo,
                                           const float* __restrict__ bufHi, int tid) {
#pragma unroll
    for (int it = 0; it < 16; ++it) {
        const int e4 = tid + it * NTHREADS;          // float4 index within pair region
        if (e4 < NPATCH * 8) {                        // 511 p * 8 float4/p = 4088
            const int p    = e4 >> 3;
            const int r    = e4 & 7;
            const int csub = r >> 2;                  // 0 -> cbase, 1 -> cbase+1
            const int j0   = (r & 3) * 4;
            const float* src = csub ? bufHi : bufLo;
            const float4 v = *(const float4*)&src[8 * p + j0];   // 8p+j0 % 4 == 0
            *(float4*)&out_bn[(size_t)p * 2048 + (cbase + csub) * 16 + j0] = v;
        }
    }
}

__global__ __launch_bounds__(NTHREADS, 2) void swt_patch(const float* __restrict__ x,
                                                         float* __restrict__ out) {
    __shared__ float bufX[T_LEN];   // x, then A2
    __shared__ float bufA[T_LEN];   // A1, then A3
    __shared__ float bufDa[T_LEN];  // D1, then D3
    __shared__ float bufDb[T_LEN];  // D2

    // XCD swizzle: same-b blocks share blockIdx%8 -> same XCD -> L2 absorbs the
    // 32x reuse of each 128B input line across the 32 n-blocks of one b.
    const int i = blockIdx.x;        // 0..2047
    const int r = i & 7;
    const int q = i >> 3;            // 0..255
    const int b = r + 8 * (q >> 5);  // 0..63
    const int n = q & 31;
    const int tid = threadIdx.x;

    // ---- phase 0: load series x[b, :, n] (stride 32 floats) into LDS ----
    const float* xp = x + (size_t)b * T_LEN * NCHAN + n;
#pragma unroll
    for (int k = 0; k < 16; ++k) {
        const int t = tid + k * NTHREADS;
        bufX[t] = xp[(size_t)t * NCHAN];
    }
    __syncthreads();

    float* out_bn = out + (size_t)b * NPATCH * 2048 + (size_t)n * 64;
    const float4* X4 = (const float4*)bufX;
    const float4* A4 = (const float4*)bufA;

    // ---- level 1 (d=1): X -> A1(bufA), D1(bufDa). Window x[t4-4 .. t4+7]. ----
#pragma unroll
    for (int k = 0; k < 4; ++k) {
        const int t4 = 4 * (tid + k * NTHREADS);
        float w[12];
        *(float4*)&w[0] = X4[((t4 - 4) & T_MASK) >> 2];
        *(float4*)&w[4] = X4[t4 >> 2];
        *(float4*)&w[8] = X4[((t4 + 4) & T_MASK) >> 2];
        float4 va, vd;
        float* pa = (float*)&va; float* pd = (float*)&vd;
#pragma unroll
        for (int ii = 0; ii < 4; ++ii) {
            float sa = 0.f, sd = 0.f;
#pragma unroll
            for (int j = 0; j < 8; ++j) {           // tap rel = ii + 8 - j
                const float v = w[ii + 8 - j];
                sa = fmaf(c_lo[j], v, sa);
                sd = fmaf(c_hi[j], v, sd);
            }
            pa[ii] = sa; pd[ii] = sd;
        }
        ((float4*)bufA)[t4 >> 2]  = va;
        ((float4*)bufDa)[t4 >> 2] = vd;
    }
    __syncthreads();

    // ---- level 2 (d=2): A1 -> A2(bufX), D2(bufDb). Window A1[t4-8 .. t4+11]. ----
#pragma unroll
    for (int k = 0; k < 4; ++k) {
        const int t4 = 4 * (tid + k * NTHREADS);
        float w[20];
        *(float4*)&w[0]  = A4[((t4 - 8) & T_MASK) >> 2];
        *(float4*)&w[4]  = A4[((t4 - 4) & T_MASK) >> 2];
        *(float4*)&w[8]  = A4[t4 >> 2];
        *(float4*)&w[12] = A4[((t4 + 4) & T_MASK) >> 2];
        *(float4*)&w[16] = A4[((t4 + 8) & T_MASK) >> 2];
        float4 va, vd;
        float* pa = (float*)&va; float* pd = (float*)&vd;
#pragma unroll
        for (int ii = 0; ii < 4; ++ii) {
            float sa = 0.f, sd = 0.f;
#pragma unroll
            for (int j = 0; j < 8; ++j) {           // tap rel = ii + 16 - 2j
                const float v = w[ii + 16 - 2 * j];
                sa = fmaf(c_lo[j], v, sa);
                sd = fmaf(c_hi[j], v, sd);
            }
            pa[ii] = sa; pd[ii] = sd;
        }
        ((float4*)bufX)[t4 >> 2]  = va;   // A2 overwrites x (x dead after level 1)
        ((float4*)bufDb)[t4 >> 2] = vd;
    }
    __syncthreads();

    // ---- store c=2 (D2, bufDb) and c=3 (D1, bufDa): full-line float4 writes ----
    store_pair(out_bn, 2, bufDb, bufDa, tid);
    __syncthreads();

    // ---- level 3 (d=4): A2(bufX) -> A3(bufA), D3(bufDa). Window A2[t4-12 .. t4+19]. ----
#pragma unroll
    for (int k = 0; k < 4; ++k) {
        const int t4 = 4 * (tid + k * NTHREADS);
        float w[32];
#pragma unroll
        for (int c4 = 0; c4 < 8; ++c4)
            *(float4*)&w[4 * c4] = X4[((t4 - 12 + 4 * c4) & T_MASK) >> 2];
        float4 va, vd;
        float* pa = (float*)&va; float* pd = (float*)&vd;
#pragma unroll
        for (int ii = 0; ii < 4; ++ii) {
            float sa = 0.f, sd = 0.f;
#pragma unroll
            for (int j = 0; j < 8; ++j) {           // tap rel = ii + 28 - 4j
                const float v = w[ii + 28 - 4 * j];
                sa = fmaf(c_lo[j], v, sa);
                sd = fmaf(c_hi[j], v, sd);
            }
            pa[ii] = sa; pd[ii] = sd;
        }
        ((float4*)bufA)[t4 >> 2]  = va;   // A3 overwrites A1 (dead after level 2)
        ((float4*)bufDa)[t4 >> 2] = vd;   // D3 overwrites D1 (stored above)
    }
    __syncthreads();

    // ---- store c=0 (A3, bufA) and c=1 (D3, bufDa) ----
    store_pair(out_bn, 0, bufA, bufDa, tid);
}

extern "C" void kernel_launch(void* const* d_in, const int* in_sizes, int n_in,
                              void* d_out, int out_size, void* d_ws, size_t ws_size,
                              hipStream_t stream) {
    const float* x = (const float*)d_in[0];
    float* out = (float*)d_out;
    hipLaunchKernelGGL(swt_patch, dim3(64 * 32), dim3(NTHREADS), 0, stream, x, out);
}

// Round 3
// 290.399 us; speedup vs baseline: 1.3028x; 1.0960x over previous
//
#include <hip/hip_runtime.h>

// WaveletPatcher: 3-level a-trous db4 SWT (periodic) + overlapping patch extract.
// x: (64, 4096, 32) f32  ->  out: (64*511, 32*4, 16) f32
//   A_{l+1}[t] = sum_j LO[j] * A_l[(t + (4-j)*d) & 4095],  d = 2^l
// c=0:A3, 1:D3, 2:D2, 3:D1.  out[(b*511+p)*2048 + n*64 + c*16 + j], t = 8p+j.
//
// R2 lesson: (b,n)-per-block => strided scalar input gathers + 8KB-strided store
// fragments => ~145us kernel. R3: block = (b, 8-patch chunk) x all 32 n:
//  - coalesced float4 input loads (contiguous in n), LDS transpose to [n][t]
//  - cascade in LDS with halo (chunk recompute, 2x input fetch total = 64MB)
//  - 8 patches/block = ONE contiguous 64KB store region, pure float4 streaming
// LDS strides padded (132/116/108/76) => 8 distinct bank-start groups, aligned b128.

#define NTHREADS 256
#define T_MASK   4095

// float offsets into the shared pool
#define S_IN  132   // IN stride  (covers t rel [-23, 104], idx = trel+23)
#define S_A1  116   // A1 stride  (covers trel [-20, 95],   idx = trel+20)
#define S_A2  108   // A2 stride  (covers trel [-12, 95],   idx = trel+12)
#define S_ST  76    // stage stride (trel [0, 71])
#define OFF_IN 0
#define OFF_A1 4224                 // 32*132
#define OFF_A2 0                    // aliases IN (x dead after level 1)
#define OFF_ST 7936                 // 4224 + 32*116
#define ST_C   2436                 // 32*76 + 4 pad (bank de-phase between c)
#define LDS_FLOATS (OFF_ST + 4*ST_C)   // 17680 floats = 70720 B -> 2 blocks/CU

__device__ __constant__ float c_lo[8] = {
    -0.010597401784997278f, 0.032883011666982945f, 0.030841381835986965f,
    -0.18703481171888114f, -0.02798376941698385f, 0.6308807679295904f,
    0.7148465705525415f,   0.23037781330885523f};
__device__ __constant__ float c_hi[8] = {
    -0.23037781330885523f, 0.7148465705525415f, -0.6308807679295904f,
    -0.02798376941698385f, 0.18703481171888114f, 0.030841381835986965f,
    -0.032883011666982945f, -0.010597401784997278f};

__global__ __launch_bounds__(NTHREADS, 2) void swt_patch(const float* __restrict__ x,
                                                         float* __restrict__ out) {
    __shared__ float lds[LDS_FLOATS];

    const int blk = blockIdx.x;        // 0..4095
    const int b   = blk >> 6;          // 0..63
    const int cid = blk & 63;          // chunk id
    const int T0  = cid << 6;          // first patch-start t
    const int p0  = cid << 3;          // first patch index (8 per chunk)
    const int tid = threadIdx.x;

    // ---- phase 0: load x[b, T0-23 .. T0+104, all n], transpose into IN[n][trel+23] ----
    // 1024 float4 loads (i = t-window index 0..127, n4 = n-quad 0..7): fully coalesced.
    const float* xb = x + (size_t)b * (4096 * 32);
    {
#pragma unroll
        for (int it = 0; it < 4; ++it) {
            const int id = tid + it * NTHREADS;        // 0..1023
            const int i  = id >> 3;                    // t-window idx
            const int n0 = (id & 7) * 4;
            const int t  = (T0 - 23 + i) & T_MASK;
            const float4 v = *(const float4*)&xb[(size_t)t * 32 + n0];
            lds[OFF_IN + (n0 + 0) * S_IN + i] = v.x;
            lds[OFF_IN + (n0 + 1) * S_IN + i] = v.y;
            lds[OFF_IN + (n0 + 2) * S_IN + i] = v.z;
            lds[OFF_IN + (n0 + 3) * S_IN + i] = v.w;
        }
    }
    __syncthreads();

    // ---- level 1 (d=1): IN -> A1 (trel -20..95), D1 -> stage c=3 (trel 0..71) ----
    // quad trel0 = -20+4q, q=0..28; window [trel0-3, trel0+7] = IN idx [4q, 4q+10] (aligned)
    for (int tsk = tid; tsk < 29 * 32; tsk += NTHREADS) {
        const int n = tsk & 31, q = tsk >> 5;
        const int trel0 = -20 + 4 * q;
        float w[12];
        const int base = OFF_IN + n * S_IN + 4 * q;
        *(float4*)&w[0] = *(const float4*)&lds[base];
        *(float4*)&w[4] = *(const float4*)&lds[base + 4];
        *(float4*)&w[8] = *(const float4*)&lds[base + 8];
        float4 va, vd;
        float* pa = (float*)&va; float* pd = (float*)&vd;
#pragma unroll
        for (int ii = 0; ii < 4; ++ii) {
            float sa = 0.f, sd = 0.f;
#pragma unroll
            for (int j = 0; j < 8; ++j) {              // tap t = trel0+ii+(4-j) -> w[ii+7-j]
                const float v = w[ii + 7 - j];
                sa = fmaf(c_lo[j], v, sa);
                sd = fmaf(c_hi[j], v, sd);
            }
            pa[ii] = sa; pd[ii] = sd;
        }
        *(float4*)&lds[OFF_A1 + n * S_A1 + (trel0 + 20)] = va;
        if (trel0 >= 0 && trel0 <= 68)
            *(float4*)&lds[OFF_ST + 3 * ST_C + n * S_ST + trel0] = vd;
    }
    __syncthreads();

    // ---- level 2 (d=2): A1 -> A2 (trel -12..87, overwrites IN), D2 -> stage c=2 ----
    // quad trel0 = -12+4q, q=0..24; window [trel0-6, trel0+11] subset of A1 idx [4q, 4q+19]
    for (int tsk = tid; tsk < 25 * 32; tsk += NTHREADS) {
        const int n = tsk & 31, q = tsk >> 5;
        const int trel0 = -12 + 4 * q;
        float w[20];
        const int base = OFF_A1 + n * S_A1 + 4 * q;    // A1 idx 4q <-> trel trel0-8
#pragma unroll
        for (int c4 = 0; c4 < 5; ++c4)
            *(float4*)&w[4 * c4] = *(const float4*)&lds[base + 4 * c4];
        float4 va, vd;
        float* pa = (float*)&va; float* pd = (float*)&vd;
#pragma unroll
        for (int ii = 0; ii < 4; ++ii) {
            float sa = 0.f, sd = 0.f;
#pragma unroll
            for (int j = 0; j < 8; ++j) {              // tap trel0+ii+2(4-j) -> w[ii+16-2j]
                const float v = w[ii + 16 - 2 * j];
                sa = fmaf(c_lo[j], v, sa);
                sd = fmaf(c_hi[j], v, sd);
            }
            pa[ii] = sa; pd[ii] = sd;
        }
        *(float4*)&lds[OFF_A2 + n * S_A2 + (trel0 + 12)] = va;
        if (trel0 >= 0 && trel0 <= 68)
            *(float4*)&lds[OFF_ST + 2 * ST_C + n * S_ST + trel0] = vd;
    }
    __syncthreads();

    // ---- level 3 (d=4): A2 -> A3 (stage c=0), D3 (stage c=1), trel 0..71 ----
    // quad trel0 = 4q, q=0..17; window [trel0-12, trel0+19] = A2 idx [trel0, trel0+31]
    for (int tsk = tid; tsk < 18 * 32; tsk += NTHREADS) {
        const int n = tsk & 31, q = tsk >> 5;
        const int trel0 = 4 * q;
        float w[32];
        const int base = OFF_A2 + n * S_A2 + trel0;    // A2 idx trel0 <-> trel trel0-12
#pragma unroll
        for (int c4 = 0; c4 < 8; ++c4)
            *(float4*)&w[4 * c4] = *(const float4*)&lds[base + 4 * c4];
        float4 va, vd;
        float* pa = (float*)&va; float* pd = (float*)&vd;
#pragma unroll
        for (int ii = 0; ii < 4; ++ii) {
            float sa = 0.f, sd = 0.f;
#pragma unroll
            for (int j = 0; j < 8; ++j) {              // tap trel0+ii+4(4-j) -> w[ii+28-4j]
                const float v = w[ii + 28 - 4 * j];
                sa = fmaf(c_lo[j], v, sa);
                sd = fmaf(c_hi[j], v, sd);
            }
            pa[ii] = sa; pd[ii] = sd;
        }
        *(float4*)&lds[OFF_ST + 0 * ST_C + n * S_ST + trel0] = va;
        *(float4*)&lds[OFF_ST + 1 * ST_C + n * S_ST + trel0] = vd;
    }
    __syncthreads();

    // ---- store: 8 patches = ONE contiguous 64KB region, float4 streaming ----
    // region float4 idx e4: p_local = e4>>9, n = (e4>>4)&31, c = (e4>>2)&3, jq = e4&3
    float4* out4 = (float4*)(out + ((size_t)b * 511 + p0) * 2048);
#pragma unroll
    for (int it = 0; it < 16; ++it) {
        const int e4 = tid + it * NTHREADS;            // 0..4095
        const int p_local = e4 >> 9;
        if (p0 + p_local < 511) {
            const int n  = (e4 >> 4) & 31;
            const int c  = (e4 >> 2) & 3;
            const int trel = 8 * p_local + 4 * (e4 & 3);
            out4[e4] = *(const float4*)&lds[OFF_ST + c * ST_C + n * S_ST + trel];
        }
    }
}

extern "C" void kernel_launch(void* const* d_in, const int* in_sizes, int n_in,
                              void* d_out, int out_size, void* d_ws, size_t ws_size,
                              hipStream_t stream) {
    const float* x = (const float*)d_in[0];
    float* out = (float*)d_out;
    hipLaunchKernelGGL(swt_patch, dim3(64 * 64), dim3(NTHREADS), 0, stream, x, out);
}